// Round 1
// baseline (429.590 us; speedup 1.0000x reference)
//
#include <hip/hip_runtime.h>

#define N 320
#define D 64

// ---------------------------------------------------------------------------
// Kernel 1: one wave per (i,j) pair; lane = d.
// Computes k, k_xj, k_xi, tr_k_xj_xi, v_t_...; stages A and k_d plus sq and
// Gram matrix G into workspace for the two N^3 kernels.
// ---------------------------------------------------------------------------
__global__ __launch_bounds__(256) void pair_kernel(
    const float* __restrict__ x, const float* __restrict__ sigma,
    const float* __restrict__ score, const float* __restrict__ v,
    const float* __restrict__ gvs,
    float* __restrict__ out_k, float* __restrict__ out_kxj,
    float* __restrict__ out_kxi, float* __restrict__ out_tr,
    float* __restrict__ out_vt,
    float* __restrict__ wsA, float* __restrict__ wsK,
    float* __restrict__ wsSQ, float* __restrict__ wsG)
{
    int lane = threadIdx.x & 63;
    int p = blockIdx.x * 4 + (threadIdx.x >> 6);   // pair index, < N*N
    int i = p / N;
    int j = p - i * N;

    float sg = sigma[0];
    float gamma = 1.0f / (sg * sg + 1e-8f);

    float xi = x[i * D + lane];
    float xj = x[j * D + lane];
    float od = xi - xj;
    float ods = od * od;
    float gods = gamma * ods;
    float kd = __expf(-0.5f * gods);

    float kxj = gamma * kd * od * (1.0f / D);
    size_t pd = (size_t)p * D + lane;
    out_kxj[pd] = kxj;
    out_kxi[pd] = -kxj;

    float sj = score[j * D + lane];
    float Aval = (1.0f - gods) * sj * (-kxj) * gamma;
    wsA[pd] = Aval;
    wsK[pd] = kd;

    float vi = v[i * D + lane];
    float gi = gvs[i * D + lane];

    float r0 = kd;                           // sum k_d
    float r1 = gamma * (1.0f - gods) * kd;   // sum for tr
    float r2 = ods;                          // sq
    float r3 = vi * od;                      // a
    float r4 = gi * od;                      // b
    float r5 = vi * gi;                      // vdot
    float r6 = xi * xj;                      // Gram

    #pragma unroll
    for (int off = 32; off > 0; off >>= 1) {
        r0 += __shfl_xor(r0, off, 64);
        r1 += __shfl_xor(r1, off, 64);
        r2 += __shfl_xor(r2, off, 64);
        r3 += __shfl_xor(r3, off, 64);
        r4 += __shfl_xor(r4, off, 64);
        r5 += __shfl_xor(r5, off, 64);
        r6 += __shfl_xor(r6, off, 64);
    }

    if (lane == 0) {
        float kmean = r0 * (1.0f / D);
        out_k[p]  = kmean;
        out_tr[p] = r1 * (1.0f / D);
        wsSQ[p]   = r2;
        wsG[p]    = r6;
        out_vt[p] = (-2.0f * gamma * r3 * r4 + r5) * kmean * 2.0f * gamma;
    }
}

// ---------------------------------------------------------------------------
// Kernel 2: tr_k_xj_xi_t_k_xk_xi  [N,N,N]  — pure elementwise via Gram
// identity: od_ij . od_ik = Gii - Gij - Gik + Gjk.
// block = 320 threads (kk), grid = (j, i).
// ---------------------------------------------------------------------------
__global__ __launch_bounds__(N) void t6_kernel(
    const float* __restrict__ sigma,
    const float* __restrict__ k, const float* __restrict__ wsSQ,
    const float* __restrict__ wsG, float* __restrict__ out6)
{
    int kk = threadIdx.x;
    int j = blockIdx.x;
    int i = blockIdx.y;

    float sg = sigma[0];
    float gamma = 1.0f / (sg * sg + 1e-8f);
    float g2 = 4.0f * gamma * gamma;

    float Gii  = wsG[i * N + i];
    float Gij  = wsG[i * N + j];
    float kij  = k[i * N + j];
    float sqij = wsSQ[i * N + j];

    float Gjk  = wsG[j * N + kk];
    float Gik  = wsG[i * N + kk];
    float kik  = k[i * N + kk];
    float sqik = wsSQ[i * N + kk];

    float dot = Gii - Gij - Gik + Gjk;
    float t1 = dot * dot * g2;
    float t2 = -2.0f * gamma * (sqij + sqik);
    out6[((size_t)i * N + j) * N + kk] = (t1 + t2 + (float)D) * kij * kik * g2;
}

// ---------------------------------------------------------------------------
// Kernel 3: score_t_k_xk_xi_k_xi  [N,N,N] — batched GEMM over d per i:
//   S5_i[j,kk] = (1/D) * sum_d A[i,j,d] * k_d[i,kk,d]
// 64x64 tile per block, 4x4 per thread, XOR-swizzled LDS (rows are 256 B so
// unswizzled rows all start at bank 0).
// ---------------------------------------------------------------------------
__global__ __launch_bounds__(256) void s5_kernel(
    const float* __restrict__ wsA, const float* __restrict__ wsK,
    float* __restrict__ out5)
{
    __shared__ float Alds[64 * 64];
    __shared__ float Klds[64 * 64];

    int i   = blockIdx.z;
    int j0  = blockIdx.y * 64;
    int kk0 = blockIdx.x * 64;
    int tid = threadIdx.x;

    // stage: each thread 4 float4 per operand; coalesced global reads,
    // swizzled LDS writes (chunk c of row r -> chunk c ^ (r&7)).
    int cw = tid & 15, rw = tid >> 4;
    const float* Abase = wsA + (size_t)(i * N + j0) * D;
    const float* Kbase = wsK + (size_t)(i * N + kk0) * D;
    #pragma unroll
    for (int q = 0; q < 4; ++q) {
        int r = rw + 16 * q;
        float4 av = *(const float4*)(Abase + r * D + cw * 4);
        float4 kv = *(const float4*)(Kbase + r * D + cw * 4);
        int sc = ((cw ^ (r & 7)) << 2);
        *(float4*)&Alds[r * 64 + sc] = av;
        *(float4*)&Klds[r * 64 + sc] = kv;
    }
    __syncthreads();

    int tk = tid & 15, tj = tid >> 4;
    float acc[4][4];
    #pragma unroll
    for (int a = 0; a < 4; ++a)
        #pragma unroll
        for (int b = 0; b < 4; ++b) acc[a][b] = 0.0f;

    #pragma unroll
    for (int c = 0; c < 16; ++c) {
        float4 a4[4], k4[4];
        #pragma unroll
        for (int jj = 0; jj < 4; ++jj) {
            int r = tj + 16 * jj;
            a4[jj] = *(const float4*)&Alds[r * 64 + ((c ^ (r & 7)) << 2)];
        }
        #pragma unroll
        for (int kki = 0; kki < 4; ++kki) {
            int r = tk + 16 * kki;
            k4[kki] = *(const float4*)&Klds[r * 64 + ((c ^ (r & 7)) << 2)];
        }
        #pragma unroll
        for (int jj = 0; jj < 4; ++jj)
            #pragma unroll
            for (int kki = 0; kki < 4; ++kki)
                acc[jj][kki] += a4[jj].x * k4[kki].x + a4[jj].y * k4[kki].y
                              + a4[jj].z * k4[kki].z + a4[jj].w * k4[kki].w;
    }

    #pragma unroll
    for (int jj = 0; jj < 4; ++jj) {
        int j = j0 + tj + 16 * jj;
        #pragma unroll
        for (int kki = 0; kki < 4; ++kki) {
            int kk = kk0 + tk + 16 * kki;
            out5[((size_t)i * N + j) * N + kk] = acc[jj][kki] * (1.0f / D);
        }
    }
}

// ---------------------------------------------------------------------------
extern "C" void kernel_launch(void* const* d_in, const int* in_sizes, int n_in,
                              void* d_out, int out_size, void* d_ws, size_t ws_size,
                              hipStream_t stream) {
    const float* x     = (const float*)d_in[0];
    const float* sigma = (const float*)d_in[1];
    const float* score = (const float*)d_in[2];
    const float* v     = (const float*)d_in[3];
    const float* gvs   = (const float*)d_in[4];

    float* out = (float*)d_out;
    // output layout (floats), in reference return order:
    float* out_k   = out;                 // [N,N]      102400
    float* out_kxj = out + 102400;        // [N,N,D]    6553600
    float* out_kxi = out + 6656000;       // [N,N,D]    6553600
    float* out_tr  = out + 13209600;      // [N,N]      102400
    float* out5    = out + 13312000;      // [N,N,N]    32768000
    float* out6    = out + 46080000;      // [N,N,N]    32768000
    float* out_vt  = out + 78848000;      // [N,N]      102400

    float* ws   = (float*)d_ws;
    float* wsA  = ws;                     // [N,N,D]
    float* wsK  = ws + 6553600;           // [N,N,D]
    float* wsSQ = ws + 13107200;          // [N,N]
    float* wsG  = ws + 13209600;          // [N,N]  (total 53.2 MB)

    pair_kernel<<<dim3(N * N / 4), dim3(256), 0, stream>>>(
        x, sigma, score, v, gvs,
        out_k, out_kxj, out_kxi, out_tr, out_vt, wsA, wsK, wsSQ, wsG);

    t6_kernel<<<dim3(N, N), dim3(N), 0, stream>>>(sigma, out_k, wsSQ, wsG, out6);

    s5_kernel<<<dim3(5, 5, N), dim3(256), 0, stream>>>(wsA, wsK, out5);
}

// Round 3
// 367.501 us; speedup vs baseline: 1.1690x; 1.1690x over previous
//
#include <hip/hip_runtime.h>

#define N 320
#define D 64

// ---------------------------------------------------------------------------
// Kernel 1: 16 lanes per (i,j) pair, float4 per lane (d = sub*4 .. sub*4+3).
// Computes k, k_xj, k_xi, tr_k_xj_xi, v_t_...; stages sq and Gram G (tiny).
// ---------------------------------------------------------------------------
__global__ __launch_bounds__(256) void pair_kernel(
    const float* __restrict__ x, const float* __restrict__ sigma,
    const float* __restrict__ score, const float* __restrict__ v,
    const float* __restrict__ gvs,
    float* __restrict__ out_k, float* __restrict__ out_kxj,
    float* __restrict__ out_kxi, float* __restrict__ out_tr,
    float* __restrict__ out_vt,
    float* __restrict__ wsSQ, float* __restrict__ wsG)
{
    int tid = threadIdx.x;
    int sub = tid & 15;                       // d-quad index
    int p = blockIdx.x * 16 + (tid >> 4);     // pair index, < N*N
    int i = p / N;
    int j = p - i * N;

    float sg = sigma[0];
    float gamma = 1.0f / (sg * sg + 1e-8f);

    float4 xi4 = *(const float4*)(x     + i * D + sub * 4);
    float4 xj4 = *(const float4*)(x     + j * D + sub * 4);
    float4 sj4 = *(const float4*)(score + j * D + sub * 4);
    float4 vi4 = *(const float4*)(v     + i * D + sub * 4);
    float4 gi4 = *(const float4*)(gvs   + i * D + sub * 4);
    const float* xi = (const float*)&xi4;
    const float* xj = (const float*)&xj4;
    const float* vi = (const float*)&vi4;
    const float* gi = (const float*)&gi4;

    float4 kxj4, kxi4;
    float* kxjp = (float*)&kxj4;
    float* kxip = (float*)&kxi4;

    float r0 = 0.f, r1 = 0.f, r2 = 0.f, r3 = 0.f, r4 = 0.f, r5 = 0.f, r6 = 0.f;
    #pragma unroll
    for (int c = 0; c < 4; ++c) {
        float od   = xi[c] - xj[c];
        float ods  = od * od;
        float gods = gamma * ods;
        float kd   = __expf(-0.5f * gods);
        float kxj  = gamma * kd * od * (1.0f / D);
        kxjp[c] = kxj;
        kxip[c] = -kxj;
        r0 += kd;
        r1 += gamma * (1.0f - gods) * kd;
        r2 += ods;
        r3 += vi[c] * od;
        r4 += gi[c] * od;
        r5 += vi[c] * gi[c];
        r6 += xi[c] * xj[c];
    }

    size_t pd = (size_t)p * D + sub * 4;
    *(float4*)(out_kxj + pd) = kxj4;
    *(float4*)(out_kxi + pd) = kxi4;

    #pragma unroll
    for (int off = 8; off > 0; off >>= 1) {
        r0 += __shfl_xor(r0, off, 64);
        r1 += __shfl_xor(r1, off, 64);
        r2 += __shfl_xor(r2, off, 64);
        r3 += __shfl_xor(r3, off, 64);
        r4 += __shfl_xor(r4, off, 64);
        r5 += __shfl_xor(r5, off, 64);
        r6 += __shfl_xor(r6, off, 64);
    }

    if (sub == 0) {
        float kmean = r0 * (1.0f / D);
        out_k[p]  = kmean;
        out_tr[p] = r1 * (1.0f / D);
        wsSQ[p]   = r2;
        wsG[p]    = r6;
        out_vt[p] = (-2.0f * gamma * r3 * r4 + r5) * kmean * 2.0f * gamma;
    }
}

// ---------------------------------------------------------------------------
// Kernel 2: fused N^3 — computes BOTH
//   out5[i,j,kk] = (1/D) * sum_d A[i,j,d] * k_d[i,kk,d]   (A, k_d on the fly)
//   out6[i,j,kk] = (dot^2*4g^2 - 2g(sq_ij+sq_ik) + D) * k_ij * k_ik * 4g^2
// 64x64 tile per block, 4x4 per thread, XOR-swizzled LDS. A/k_d tiles are
// recomputed from x/score (L1-resident) — no big workspace round-trip.
// ---------------------------------------------------------------------------
__global__ __launch_bounds__(256) void triple_kernel(
    const float* __restrict__ x, const float* __restrict__ sigma,
    const float* __restrict__ score,
    const float* __restrict__ kmat, const float* __restrict__ wsSQ,
    const float* __restrict__ wsG,
    float* __restrict__ out5, float* __restrict__ out6)
{
    __shared__ float Alds[64 * 64];
    __shared__ float Klds[64 * 64];

    int i   = blockIdx.z;
    int j0  = blockIdx.y * 64;
    int kk0 = blockIdx.x * 64;
    int tid = threadIdx.x;

    float sg = sigma[0];
    float gamma = 1.0f / (sg * sg + 1e-8f);
    float cA = -gamma * gamma * (1.0f / D);   // A = cA*(1-gods)*score*kd*od
    float g2 = 4.0f * gamma * gamma;

    // ---- stage: compute A-tile (rows j0..j0+63) and K-tile (rows kk0..) ----
    int cw = tid & 15, rw = tid >> 4;
    float4 xi4 = *(const float4*)(x + i * D + cw * 4);
    const float* xi = (const float*)&xi4;
    #pragma unroll
    for (int q = 0; q < 4; ++q) {
        int r = rw + 16 * q;
        float4 xj4 = *(const float4*)(x     + (j0  + r) * D + cw * 4);
        float4 sj4 = *(const float4*)(score + (j0  + r) * D + cw * 4);
        float4 xk4 = *(const float4*)(x     + (kk0 + r) * D + cw * 4);
        const float* xj = (const float*)&xj4;
        const float* sj = (const float*)&sj4;
        const float* xk = (const float*)&xk4;
        float4 av, kv;
        float* avp = (float*)&av;
        float* kvp = (float*)&kv;
        #pragma unroll
        for (int c = 0; c < 4; ++c) {
            float odA  = xi[c] - xj[c];
            float odsA = odA * odA;
            float kdA  = __expf(-0.5f * gamma * odsA);
            avp[c] = cA * (1.0f - gamma * odsA) * sj[c] * kdA * odA;
            float odK = xi[c] - xk[c];
            kvp[c] = __expf(-0.5f * gamma * odK * odK);
        }
        int sc = ((cw ^ (r & 7)) << 2);
        *(float4*)&Alds[r * 64 + sc] = av;
        *(float4*)&Klds[r * 64 + sc] = kv;
    }
    __syncthreads();

    // ---- GEMM: 4x4 register tile, K=64 ----
    int tk = tid & 15, tj = tid >> 4;
    float acc[4][4];
    #pragma unroll
    for (int a = 0; a < 4; ++a)
        #pragma unroll
        for (int b = 0; b < 4; ++b) acc[a][b] = 0.0f;

    #pragma unroll
    for (int c = 0; c < 16; ++c) {
        float4 a4[4], k4[4];
        #pragma unroll
        for (int jj = 0; jj < 4; ++jj) {
            int r = tj + 16 * jj;
            a4[jj] = *(const float4*)&Alds[r * 64 + ((c ^ (r & 7)) << 2)];
        }
        #pragma unroll
        for (int kki = 0; kki < 4; ++kki) {
            int r = tk + 16 * kki;
            k4[kki] = *(const float4*)&Klds[r * 64 + ((c ^ (r & 7)) << 2)];
        }
        #pragma unroll
        for (int jj = 0; jj < 4; ++jj)
            #pragma unroll
            for (int kki = 0; kki < 4; ++kki)
                acc[jj][kki] += a4[jj].x * k4[kki].x + a4[jj].y * k4[kki].y
                              + a4[jj].z * k4[kki].z + a4[jj].w * k4[kki].w;
    }

    // ---- epilogue: out5 + fused out6 (Gram identity) ----
    float Gii = wsG[i * N + i];
    float kikv[4], sqikv[4], Gikv[4];
    #pragma unroll
    for (int kki = 0; kki < 4; ++kki) {
        int kk = kk0 + tk + 16 * kki;
        kikv[kki]  = kmat[i * N + kk];
        sqikv[kki] = wsSQ[i * N + kk];
        Gikv[kki]  = wsG[i * N + kk];
    }
    #pragma unroll
    for (int jj = 0; jj < 4; ++jj) {
        int j = j0 + tj + 16 * jj;
        float kij  = kmat[i * N + j];
        float sqij = wsSQ[i * N + j];
        float Gij  = wsG[i * N + j];
        size_t rowbase = ((size_t)i * N + j) * N;
        #pragma unroll
        for (int kki = 0; kki < 4; ++kki) {
            int kk = kk0 + tk + 16 * kki;
            out5[rowbase + kk] = acc[jj][kki] * (1.0f / D);
            float Gjk = wsG[j * N + kk];
            float dot = Gii - Gij - Gikv[kki] + Gjk;
            float t1 = dot * dot * g2;
            float t2 = -2.0f * gamma * (sqij + sqikv[kki]);
            out6[rowbase + kk] = (t1 + t2 + (float)D) * kij * kikv[kki] * g2;
        }
    }
}

// ---------------------------------------------------------------------------
extern "C" void kernel_launch(void* const* d_in, const int* in_sizes, int n_in,
                              void* d_out, int out_size, void* d_ws, size_t ws_size,
                              hipStream_t stream) {
    const float* x     = (const float*)d_in[0];
    const float* sigma = (const float*)d_in[1];
    const float* score = (const float*)d_in[2];
    const float* v     = (const float*)d_in[3];
    const float* gvs   = (const float*)d_in[4];

    float* out = (float*)d_out;
    float* out_k   = out;                 // [N,N]      102400
    float* out_kxj = out + 102400;        // [N,N,D]    6553600
    float* out_kxi = out + 6656000;       // [N,N,D]    6553600
    float* out_tr  = out + 13209600;      // [N,N]      102400
    float* out5    = out + 13312000;      // [N,N,N]    32768000
    float* out6    = out + 46080000;      // [N,N,N]    32768000
    float* out_vt  = out + 78848000;      // [N,N]      102400

    float* ws   = (float*)d_ws;
    float* wsSQ = ws;                     // [N,N]
    float* wsG  = ws + 102400;            // [N,N]

    pair_kernel<<<dim3(N * N / 16), dim3(256), 0, stream>>>(
        x, sigma, score, v, gvs,
        out_k, out_kxj, out_kxi, out_tr, out_vt, wsSQ, wsG);

    triple_kernel<<<dim3(5, 5, N), dim3(256), 0, stream>>>(
        x, sigma, score, out_k, wsSQ, wsG, out5, out6);
}